// Round 1
// baseline (2405.354 us; speedup 1.0000x reference)
//
#include <hip/hip_runtime.h>
#include <hip/hip_bf16.h>

// Problem constants: inputs [T,B,D], state [B,H], W_xh [D,H], W_hh [H,H], b_h [H]
#define T_STEPS 256
#define B_SZ    64
#define D_SZ    1024
#define H_SZ    2048
#define NBLK    256     // persistent blocks, 1/CU (coop-launched)
#define TPB_F   384     // fused: waves 0-3 compute, wave 4 burn, wave 5 x_proj producer
#define TPB_NF  320     // fallback: waves 0-3 compute, wave 4 burn
#define HBUF    (B_SZ * H_SZ)   // one h buffer: 131072 fp16 = 256 KB

// fp16 everywhere (2^-11 rounding). Weights stored x256 so all entries are
// fp16-normal (W ~ U(0,0.01)); accumulator scaled by 1/256 in epilogue.
#define W_SCALE     256.0f
#define W_INV_SCALE 0.00390625f

typedef __attribute__((ext_vector_type(8))) _Float16 f16x8;  // 8 fp16 (4 VGPRs)
typedef __attribute__((ext_vector_type(4))) _Float16 f16x4;
typedef __attribute__((ext_vector_type(4))) float    f32x4;  // MFMA 16x16 accumulator

// ---------------- prep kernels ----------------

// vectorized f32 -> f16 (float4 in, f16x4 out); n4 = n/4
__global__ void cvt_f32_f16(const float* __restrict__ in,
                            _Float16* __restrict__ out, int n4, float scale) {
    int i = blockIdx.x * blockDim.x + threadIdx.x;
    if (i < n4) {
        float4 v = ((const float4*)in)[i];
        f16x4 o = { (_Float16)(v.x * scale), (_Float16)(v.y * scale),
                    (_Float16)(v.z * scale), (_Float16)(v.w * scale) };
        ((f16x4*)out)[i] = o;
    }
}

// LDS-tiled transpose: out[c][r] = in[r][c] * scale. Coalesced read AND write
// (old version scattered 2B writes across 64 lines/wave). rows, cols % 32 == 0.
__global__ void transpose_to_f16(const float* __restrict__ in,
                                 _Float16* __restrict__ out,
                                 int rows, int cols, float scale) {
    __shared__ float tile[32][33];
    int tx = threadIdx.x & 31, ty = threadIdx.x >> 5;   // 32x8 threads
    int r0 = blockIdx.y * 32, c0 = blockIdx.x * 32;
#pragma unroll
    for (int i = 0; i < 32; i += 8)
        tile[ty + i][tx] = in[(size_t)(r0 + ty + i) * cols + c0 + tx];
    __syncthreads();
#pragma unroll
    for (int i = 0; i < 32; i += 8)
        out[(size_t)(c0 + ty + i) * rows + r0 + tx] = (_Float16)(tile[tx][ty + i] * scale);
}

__global__ void init_ctrs(unsigned int* ctr) {
    ctr[threadIdx.x + blockIdx.x * blockDim.x] = 0u;
}

// ---------------- fallback phase 1: x_proj = inputs @ W_xh + b_h ----------------
__global__ __launch_bounds__(256) void gemm_xproj(
    const _Float16* __restrict__ A,
    const _Float16* __restrict__ BT,
    const float* __restrict__ bias,
    float* __restrict__ C,
    int M, int N, int K)
{
    int wave = threadIdx.x >> 6;
    int lane = threadIdx.x & 63;
    int q = lane >> 4;
    int r = lane & 15;
    int m0 = blockIdx.x * 128 + (wave >> 1) * 64;
    int n0 = blockIdx.y * 128 + (wave & 1) * 64;

    f32x4 acc[4][4] = {};
    for (int k = 0; k < K; k += 32) {
        int kk = k + q * 8;
        f16x8 a[4], b[4];
#pragma unroll
        for (int i = 0; i < 4; i++)
            a[i] = *(const f16x8*)(A + (size_t)(m0 + i * 16 + r) * K + kk);
#pragma unroll
        for (int j = 0; j < 4; j++)
            b[j] = *(const f16x8*)(BT + (size_t)(n0 + j * 16 + r) * K + kk);
#pragma unroll
        for (int i = 0; i < 4; i++)
#pragma unroll
            for (int j = 0; j < 4; j++)
                acc[i][j] = __builtin_amdgcn_mfma_f32_16x16x32_f16(a[i], b[j], acc[i][j], 0, 0, 0);
    }
#pragma unroll
    for (int i = 0; i < 4; i++)
#pragma unroll
        for (int j = 0; j < 4; j++)
#pragma unroll
            for (int reg = 0; reg < 4; reg++) {
                int row = m0 + i * 16 + q * 4 + reg;   // C/D: col=lane&15, row=(lane>>4)*4+reg
                int col = n0 + j * 16 + r;
                C[(size_t)row * N + col] = acc[i][j][reg] * W_INV_SCALE + bias[col];
            }
}

// ---------------- phase 2: persistent recurrence ----------------
// R10 (5.27 us/step): K split across 4 compute waves, LDS partial reduce by
// waves 0/1, flat per-group barrier, chain h buffers (fresh addresses).
// R11: x_proj GEMM FUSED into wave 5 — each block computes its own 16x32 xp
// tile (K=1024 slice = 64 MFMA + 96KB loads ~ 3k cyc, inside the 12.6k-cyc
// step budget) one step ahead, into a 2-slot LDS buffer. Producer/consumer
// via monotonic LDS flag xpready (same pattern as pdone/part). Pacing gated
// on `go` (xp[t] computed only after step t-2 done -> slot reuse race-free).
// Eliminates the ~400us gemm_xproj wall time + 256MB of fp32 xp HBM traffic.
// Burn wave (4) unchanged to preserve clock behavior.
template<bool CHAIN, bool FUSED>
__global__ __launch_bounds__(TPB_F, 1) void rnn_persist(
    _Float16* __restrict__ hbase,          // CHAIN: h_0 of chain; else ping buf
    _Float16* __restrict__ hb1,            // pong buf (fallback only)
    const _Float16* __restrict__ WT,       // [H,H] fp16 = W_hh^T x256
    const _Float16* __restrict__ xin,      // FUSED: inputs fp16 [T,B,D]
    const _Float16* __restrict__ WxT,      // FUSED: [H,D] fp16 = W_xh^T x256
    const float*    __restrict__ bias,     // FUSED: b_h [H]
    float* __restrict__ out,               // [T,B,H] fp32 (FUSED: h out only; else xp in / h out)
    float* __restrict__ final_out,         // [B,H] fp32
    unsigned int* __restrict__ ctr)        // barrier region (pre-zeroed)
{
    constexpr int NT = FUSED ? TPB_F : TPB_NF;
    __shared__ f16x8 wfrag[8192];                   // [kb][half][lane] = 128 KB
    __shared__ float part[4][2][256];               // [w][half][lane*4+reg] = 8 KB
    __shared__ __align__(16) _Float16 hsl[16 * 32]; // 1 KB block h tile
    __shared__ float xpl[2][16][32];                // 4 KB xp double buffer (FUSED)
    __shared__ int pdone[4];                        // per-wave partial flags
    __shared__ int hdone1, go, xpready;             // monotonic flags

    int tid = threadIdx.x;
    int bid = blockIdx.x;
    int g   = (bid >> 1) & 3;                    // row group (XCD-pair under round-robin)
    int c   = ((bid >> 3) << 1) | (bid & 1);     // col range 0..63
    int n0  = c * 32;
    int row0 = g * 16;                           // block's 16 batch rows

    if (tid == 0) {
        pdone[0] = pdone[1] = pdone[2] = pdone[3] = 0;
        hdone1 = 0; go = 0; xpready = 0;
    }

    // one-time W staging into fragment order: idx = (kb*2+half)*64 + l
    for (int idx = tid; idx < 8192; idx += NT) {
        int kb = idx >> 7, j = (idx >> 6) & 1, l = idx & 63;
        wfrag[idx] = *(const f16x8*)(WT + (size_t)(n0 + j * 16 + (l & 15)) * H_SZ
                                        + kb * 32 + (l >> 4) * 8);
    }
    __syncthreads();   // the ONLY block-wide barrier (covers flag init)

    int wave = tid >> 6, lane = tid & 63;

    if (wave == 4) {
        // dedicated clock keep-alive: 4 independent FMA chains, poll LDS exit flag
        float c0 = 1.0f + lane, c1 = 2.0f, c2 = 3.0f, c3 = 4.0f;
        const float k1 = 1.0000001f, k2 = 1.0e-30f;
        while (__hip_atomic_load(&go, __ATOMIC_RELAXED, __HIP_MEMORY_SCOPE_WORKGROUP) < T_STEPS) {
#pragma unroll
            for (int z = 0; z < 64; z++) {
                c0 = __builtin_fmaf(c0, k1, k2);
                c1 = __builtin_fmaf(c1, k1, k2);
                c2 = __builtin_fmaf(c2, k1, k2);
                c3 = __builtin_fmaf(c3, k1, k2);
            }
        }
        __asm__ volatile("" :: "v"(c0), "v"(c1), "v"(c2), "v"(c3));
        return;
    }

    if constexpr (FUSED) {
        if (wave == 5) {
            // xp producer: xp[t] tile (16 rows x 32 cols, K=1024) one step ahead.
            // Computes xp[t] only after go >= t-1 (step t-2 done) so slot t&1 is free.
            int q = lane >> 4, r = lane & 15;
            float bj0 = bias[n0 + r];
            float bj1 = bias[n0 + 16 + r];
            const _Float16* wr0 = WxT + (size_t)(n0 + r) * D_SZ + q * 8;
            const _Float16* wr1 = WxT + (size_t)(n0 + 16 + r) * D_SZ + q * 8;
            for (int t = 0; t < T_STEPS; t++) {
                if (t >= 2)
                    while (__hip_atomic_load(&go, __ATOMIC_RELAXED, __HIP_MEMORY_SCOPE_WORKGROUP) < t - 1) { }
                const _Float16* xr = xin + ((size_t)t * B_SZ + row0 + r) * D_SZ + q * 8;
                f32x4 xacc0 = {}, xacc1 = {};
                for (int k = 0; k < D_SZ; k += 128) {
                    f16x8 xa[4], xb0[4], xb1[4];
#pragma unroll
                    for (int p = 0; p < 4; p++) {
                        xa[p]  = *(const f16x8*)(xr  + k + p * 32);
                        xb0[p] = *(const f16x8*)(wr0 + k + p * 32);
                        xb1[p] = *(const f16x8*)(wr1 + k + p * 32);
                    }
#pragma unroll
                    for (int p = 0; p < 4; p++) {
                        xacc0 = __builtin_amdgcn_mfma_f32_16x16x32_f16(xa[p], xb0[p], xacc0, 0, 0, 0);
                        xacc1 = __builtin_amdgcn_mfma_f32_16x16x32_f16(xa[p], xb1[p], xacc1, 0, 0, 0);
                    }
                }
                // C/D layout: row = q*4+reg, col = j*16 + r  (same mapping as gemm_xproj)
                float* xs = &xpl[t & 1][0][0];
#pragma unroll
                for (int reg = 0; reg < 4; reg++) {
                    xs[(q * 4 + reg) * 32 + r]      = xacc0[reg] * W_INV_SCALE + bj0;
                    xs[(q * 4 + reg) * 32 + 16 + r] = xacc1[reg] * W_INV_SCALE + bj1;
                }
                __asm__ volatile("s_waitcnt lgkmcnt(0)" ::: "memory");
                if (lane == 0)
                    __hip_atomic_store(&xpready, t + 1, __ATOMIC_RELAXED, __HIP_MEMORY_SCOPE_WORKGROUP);
            }
            return;
        }
    }

    int q = lane >> 4, r = lane & 15;
    unsigned int* aline = ctr + (g * 2 + (bid & 1)) * 32;   // group parity arrival line

    // reducer-layout x_proj prefetch for t=0 (waves 0,1 only; non-fused path):
    // elem s -> row = (lane>>4)+4s, col = lane&15, column half = wave
    float xp[4] = {0.f, 0.f, 0.f, 0.f};
    if constexpr (!FUSED) {
        if (wave < 2) {
#pragma unroll
            for (int s = 0; s < 4; s++)
                xp[s] = out[(size_t)(row0 + q + 4 * s) * H_SZ + n0 + wave * 16 + r];
        }
    }

    for (int t = 0; t < T_STEPS; t++) {
        const _Float16* hp;
        _Float16*       hn;
        if constexpr (CHAIN) {
            hp = hbase + (size_t)t * HBUF;
            hn = hbase + (size_t)(t + 1) * HBUF;
        } else {
            hp = (t & 1) ? hb1 : hbase;
            hn = (t & 1) ? hbase : hb1;
        }
        float* out_t = out + (size_t)t * B_SZ * H_SZ;
        int tg = t + 1;

        // ---- A stream: this wave's K-slice, all 16 loads in flight ----
        const _Float16* arow = hp + (size_t)(row0 + r) * H_SZ + q * 8;
        f16x8 abuf[16];
#pragma unroll
        for (int p = 0; p < 16; p++) {
            if constexpr (CHAIN) {
                abuf[p] = *(const f16x8*)(arow + (wave * 16 + p) * 32);
            } else {
                union { unsigned long long u[2]; f16x8 v; } au;
                au.u[0] = __hip_atomic_load((unsigned long long*)(arow + (wave * 16 + p) * 32),
                                            __ATOMIC_RELAXED, __HIP_MEMORY_SCOPE_AGENT);
                au.u[1] = __hip_atomic_load((unsigned long long*)(arow + (wave * 16 + p) * 32) + 1,
                                            __ATOMIC_RELAXED, __HIP_MEMORY_SCOPE_AGENT);
                abuf[p] = au.v;
            }
        }
        f32x4 acc[2] = {};
#pragma unroll
        for (int p = 0; p < 16; p++) {
            int kb = wave * 16 + p;
            acc[0] = __builtin_amdgcn_mfma_f32_16x16x32_f16(abuf[p], wfrag[kb * 128 + lane],      acc[0], 0, 0, 0);
            acc[1] = __builtin_amdgcn_mfma_f32_16x16x32_f16(abuf[p], wfrag[kb * 128 + 64 + lane], acc[1], 0, 0, 0);
        }

        // partials to LDS (b128, conflict-free), then flag
#pragma unroll
        for (int h = 0; h < 2; h++)
            *(f32x4*)&part[wave][h][lane * 4] = acc[h];
        __asm__ volatile("s_waitcnt lgkmcnt(0)" ::: "memory");
        if (lane == 0)
            __hip_atomic_store(&pdone[wave], tg, __ATOMIC_RELAXED, __HIP_MEMORY_SCOPE_WORKGROUP);

        if (wave >= 2) {
            if (t == T_STEPS - 1) break;
            while (__hip_atomic_load(&go, __ATOMIC_RELAXED, __HIP_MEMORY_SCOPE_WORKGROUP) < tg) { }
            continue;
        }

        // ---- reducer path (wave 0 = col half 0, wave 1 = col half 1) ----
        for (int w = 0; w < 4; w++)
            if (w != wave)
                while (__hip_atomic_load(&pdone[w], __ATOMIC_RELAXED, __HIP_MEMORY_SCOPE_WORKGROUP) < tg) { }
        __asm__ volatile("" ::: "memory");

        if constexpr (FUSED) {
            // xp tile for step t must be in LDS (produced during step t-1; normally no wait)
            while (__hip_atomic_load(&xpready, __ATOMIC_RELAXED, __HIP_MEMORY_SCOPE_WORKGROUP) < tg) { }
            __asm__ volatile("" ::: "memory");
        }

        bool last = (t == T_STEPS - 1);
#pragma unroll
        for (int s = 0; s < 4; s++) {
            int row = q + 4 * s;                  // local row 0..15
            int idx = (s * 16 + r) * 4 + q;       // producer layout: ((row>>2)*16+col)*4+(row&3)
            float sum = part[0][wave][idx] + part[1][wave][idx]
                      + part[2][wave][idx] + part[3][wave][idx];
            float xv;
            if constexpr (FUSED) xv = xpl[t & 1][row][wave * 16 + r];
            else                 xv = xp[s];
            float v = tanhf(sum * W_INV_SCALE + xv);
            size_t o = (size_t)(row0 + row) * H_SZ + n0 + wave * 16 + r;
            out_t[o] = v;
            if (last) final_out[o] = v;
            hsl[row * 32 + wave * 16 + r] = (_Float16)v;
        }
        if (last) {
            if (wave == 0 && lane == 0)
                __hip_atomic_store(&go, T_STEPS, __ATOMIC_RELAXED, __HIP_MEMORY_SCOPE_WORKGROUP);
            break;
        }

        if constexpr (!FUSED) {
            // prefetch next step's x_proj (h-independent; overlaps h store)
            const float* out_t1 = out_t + B_SZ * H_SZ;
#pragma unroll
            for (int s = 0; s < 4; s++)
                xp[s] = out_t1[(size_t)(row0 + q + 4 * s) * H_SZ + n0 + wave * 16 + r];
        }

        // h store: this wave's column half, 16 rows x 4 ull = 64 ull, 1/lane
        __asm__ volatile("s_waitcnt lgkmcnt(0)" ::: "memory");
        {
            int rl = lane >> 2, pi = wave * 4 + (lane & 3);
            unsigned long long vv = ((const unsigned long long*)hsl)[rl * 8 + pi];
            __hip_atomic_store((unsigned long long*)(hn + (size_t)(row0 + rl) * H_SZ + n0) + pi,
                               vv, __ATOMIC_RELAXED, __HIP_MEMORY_SCOPE_AGENT);
        }
        __builtin_amdgcn_s_waitcnt(0);   // h stores acked at coherence point

        if (wave == 1) {
            if (lane == 0)
                __hip_atomic_store(&hdone1, tg, __ATOMIC_RELAXED, __HIP_MEMORY_SCOPE_WORKGROUP);
            while (__hip_atomic_load(&go, __ATOMIC_RELAXED, __HIP_MEMORY_SCOPE_WORKGROUP) < tg) { }
            continue;
        }
        // wave 0: group barrier (flat: add + poll both parity lines)
        while (__hip_atomic_load(&hdone1, __ATOMIC_RELAXED, __HIP_MEMORY_SCOPE_WORKGROUP) < tg) { }
        if (lane == 0)
            __hip_atomic_fetch_add(aline, 1u, __ATOMIC_RELAXED, __HIP_MEMORY_SCOPE_AGENT);
        unsigned int line_tgt = (unsigned int)tg * 32u;
        for (;;) {
            unsigned int v = __hip_atomic_load(ctr + (g * 2 + (lane & 1)) * 32,
                                               __ATOMIC_RELAXED, __HIP_MEMORY_SCOPE_AGENT);
            if (__ballot(v < line_tgt) == 0ull) break;
        }
        if (lane == 0)
            __hip_atomic_store(&go, tg, __ATOMIC_RELAXED, __HIP_MEMORY_SCOPE_WORKGROUP);
    }
}

// ---------------- launcher ----------------

extern "C" void kernel_launch(void* const* d_in, const int* in_sizes, int n_in,
                              void* d_out, int out_size, void* d_ws, size_t ws_size,
                              hipStream_t stream) {
    const float* inputs = (const float*)d_in[0];   // [T,B,D]
    const float* state  = (const float*)d_in[1];   // [B,H]
    const float* W_xh   = (const float*)d_in[2];   // [D,H]
    const float* W_hh   = (const float*)d_in[3];   // [H,H]
    const float* b_h    = (const float*)d_in[4];   // [H]
    float* out = (float*)d_out;
    char* ws = (char*)d_ws;

    const size_t MB = 1ull << 20;
    const size_t XIN_BYTES = (size_t)T_STEPS * B_SZ * D_SZ * 2;   // 32 MB fp16 inputs

    // fused layout: [WxT 4MB][WhT 8MB][ctr 8KB][inputs_f16 32MB][h chain 257x256KB]
    // inputs_f16 can NOT alias the chain (read live during the persistent kernel).
    const size_t OFF_WXT     = 0;
    const size_t OFF_WHT     = 4 * MB;
    const size_t OFF_CTR     = 12 * MB;
    const size_t OFF_XIN     = 12 * MB + 8192;
    const size_t OFF_CHAIN_F = OFF_XIN + XIN_BYTES;
    const size_t NEED_FUSED  = OFF_CHAIN_F + (size_t)(T_STEPS + 1) * HBUF * 2;

    // old chain layout (separate gemm; inputs_f16 aliases chain slots h_1..h_128)
    const size_t OFF_CHAIN  = 12 * MB + 8192;
    const size_t NEED_CHAIN = OFF_CHAIN + (size_t)(T_STEPS + 1) * HBUF * 2;

    // fallback (ping-pong) layout
    const size_t F_IN  = 0;
    const size_t F_WXT = F_IN  + XIN_BYTES;
    const size_t F_WHT = F_WXT + (size_t)H_SZ * D_SZ * 2;
    const size_t F_H0  = F_WHT + (size_t)H_SZ * H_SZ * 2;
    const size_t F_H1  = F_H0  + (size_t)HBUF * 2;
    const size_t F_CTR = F_H1  + (size_t)HBUF * 2;
    const size_t NEED_PP = F_CTR + 4096;

    const int n_in_el = T_STEPS * B_SZ * D_SZ;   // 16,777,216 (div by 4)
    dim3 g1((T_STEPS * B_SZ) / 128, H_SZ / 128);
    float* final_out = out + (size_t)T_STEPS * B_SZ * H_SZ;

    if (ws_size >= NEED_FUSED) {
        _Float16* WxT     = (_Float16*)(ws + OFF_WXT);
        _Float16* WhT     = (_Float16*)(ws + OFF_WHT);
        unsigned int* ctr = (unsigned int*)(ws + OFF_CTR);
        _Float16* xin     = (_Float16*)(ws + OFF_XIN);
        _Float16* hchain  = (_Float16*)(ws + OFF_CHAIN_F);
        _Float16* hb1 = nullptr;

        cvt_f32_f16<<<(n_in_el / 4 + 255) / 256, 256, 0, stream>>>(inputs, xin, n_in_el / 4, 1.0f);
        transpose_to_f16<<<dim3(H_SZ / 32, D_SZ / 32), 256, 0, stream>>>(W_xh, WxT, D_SZ, H_SZ, W_SCALE);
        transpose_to_f16<<<dim3(H_SZ / 32, H_SZ / 32), 256, 0, stream>>>(W_hh, WhT, H_SZ, H_SZ, W_SCALE);
        cvt_f32_f16<<<(B_SZ * H_SZ / 4 + 255) / 256, 256, 0, stream>>>(state, hchain, B_SZ * H_SZ / 4, 1.0f);
        init_ctrs<<<4, 256, 0, stream>>>(ctr);

        const _Float16* WhT_c  = WhT;
        const _Float16* xin_c  = xin;
        const _Float16* WxT_c  = WxT;
        const float*    bias_c = b_h;
        void* args[] = { (void*)&hchain, (void*)&hb1, (void*)&WhT_c, (void*)&xin_c,
                         (void*)&WxT_c, (void*)&bias_c, (void*)&out, (void*)&final_out,
                         (void*)&ctr };
        hipLaunchCooperativeKernel((void*)rnn_persist<true, true>, dim3(NBLK), dim3(TPB_F),
                                   args, 0, stream);
    } else if (ws_size >= NEED_CHAIN) {
        _Float16* WxT     = (_Float16*)(ws + OFF_WXT);
        _Float16* WhT     = (_Float16*)(ws + OFF_WHT);
        unsigned int* ctr = (unsigned int*)(ws + OFF_CTR);
        _Float16* hchain  = (_Float16*)(ws + OFF_CHAIN);
        _Float16* inputs_f16 = hchain + HBUF;                    // alias h_1..h_128
        _Float16* hb1 = nullptr;

        cvt_f32_f16<<<(n_in_el / 4 + 255) / 256, 256, 0, stream>>>(inputs, inputs_f16, n_in_el / 4, 1.0f);
        transpose_to_f16<<<dim3(H_SZ / 32, D_SZ / 32), 256, 0, stream>>>(W_xh, WxT, D_SZ, H_SZ, W_SCALE);
        transpose_to_f16<<<dim3(H_SZ / 32, H_SZ / 32), 256, 0, stream>>>(W_hh, WhT, H_SZ, H_SZ, W_SCALE);
        cvt_f32_f16<<<(B_SZ * H_SZ / 4 + 255) / 256, 256, 0, stream>>>(state, hchain, B_SZ * H_SZ / 4, 1.0f);
        init_ctrs<<<4, 256, 0, stream>>>(ctr);

        gemm_xproj<<<g1, 256, 0, stream>>>(inputs_f16, WxT, b_h, out,
                                           T_STEPS * B_SZ, H_SZ, D_SZ);

        const _Float16* WhT_c  = WhT;
        const _Float16* xin_c  = nullptr;
        const _Float16* WxT_c  = nullptr;
        const float*    bias_c = nullptr;
        void* args[] = { (void*)&hchain, (void*)&hb1, (void*)&WhT_c, (void*)&xin_c,
                         (void*)&WxT_c, (void*)&bias_c, (void*)&out, (void*)&final_out,
                         (void*)&ctr };
        hipLaunchCooperativeKernel((void*)rnn_persist<true, false>, dim3(NBLK), dim3(TPB_NF),
                                   args, 0, stream);
    } else {
        if (ws_size < NEED_PP) return;
        _Float16* inputs_f16 = (_Float16*)(ws + F_IN);
        _Float16* WxT    = (_Float16*)(ws + F_WXT);
        _Float16* WhT    = (_Float16*)(ws + F_WHT);
        _Float16* hbuf0  = (_Float16*)(ws + F_H0);
        _Float16* hbuf1  = (_Float16*)(ws + F_H1);
        unsigned int* ctr = (unsigned int*)(ws + F_CTR);

        cvt_f32_f16<<<(n_in_el / 4 + 255) / 256, 256, 0, stream>>>(inputs, inputs_f16, n_in_el / 4, 1.0f);
        transpose_to_f16<<<dim3(H_SZ / 32, D_SZ / 32), 256, 0, stream>>>(W_xh, WxT, D_SZ, H_SZ, W_SCALE);
        transpose_to_f16<<<dim3(H_SZ / 32, H_SZ / 32), 256, 0, stream>>>(W_hh, WhT, H_SZ, H_SZ, W_SCALE);
        cvt_f32_f16<<<(B_SZ * H_SZ / 4 + 255) / 256, 256, 0, stream>>>(state, hbuf0, B_SZ * H_SZ / 4, 1.0f);
        init_ctrs<<<4, 256, 0, stream>>>(ctr);

        gemm_xproj<<<g1, 256, 0, stream>>>(inputs_f16, WxT, b_h, out,
                                           T_STEPS * B_SZ, H_SZ, D_SZ);

        const _Float16* WhT_c  = WhT;
        const _Float16* xin_c  = nullptr;
        const _Float16* WxT_c  = nullptr;
        const float*    bias_c = nullptr;
        void* args[] = { (void*)&hbuf0, (void*)&hbuf1, (void*)&WhT_c, (void*)&xin_c,
                         (void*)&WxT_c, (void*)&bias_c, (void*)&out, (void*)&final_out,
                         (void*)&ctr };
        hipLaunchCooperativeKernel((void*)rnn_persist<false, false>, dim3(NBLK), dim3(TPB_NF),
                                   args, 0, stream);
    }
}

// Round 2
// 1653.758 us; speedup vs baseline: 1.4545x; 1.4545x over previous
//
#include <hip/hip_runtime.h>
#include <hip/hip_bf16.h>

// Problem constants: inputs [T,B,D], state [B,H], W_xh [D,H], W_hh [H,H], b_h [H]
#define T_STEPS 256
#define B_SZ    64
#define D_SZ    1024
#define H_SZ    2048
#define NBLK    256     // persistent blocks, 1/CU (coop-launched)
#define TPB     320     // waves 0-3 = compute (K-split), wave 4 = clock-burn
#define HBUF    (B_SZ * H_SZ)   // one h buffer: 131072 fp16 = 256 KB

// fp16 everywhere (2^-11 rounding). Weights stored x256 so all entries are
// fp16-normal (W ~ U(0,0.01)); accumulator scaled by 1/256 in epilogue.
#define W_SCALE     256.0f
#define W_INV_SCALE 0.00390625f

typedef __attribute__((ext_vector_type(8))) _Float16 f16x8;  // 8 fp16 (4 VGPRs)
typedef __attribute__((ext_vector_type(4))) _Float16 f16x4;
typedef __attribute__((ext_vector_type(4))) float    f32x4;  // MFMA 16x16 accumulator

// ---------------- prep kernels ----------------

// vectorized f32 -> f16 (float4 in, f16x4 out); n4 = n/4
__global__ void cvt_f32_f16(const float* __restrict__ in,
                            _Float16* __restrict__ out, int n4, float scale) {
    int i = blockIdx.x * blockDim.x + threadIdx.x;
    if (i < n4) {
        float4 v = ((const float4*)in)[i];
        f16x4 o = { (_Float16)(v.x * scale), (_Float16)(v.y * scale),
                    (_Float16)(v.z * scale), (_Float16)(v.w * scale) };
        ((f16x4*)out)[i] = o;
    }
}

// LDS-tiled transpose: out[c][r] = in[r][c] * scale. Coalesced read AND write
// (old version scattered 2B writes across 64 lines/wave). rows, cols % 32 == 0.
__global__ void transpose_to_f16(const float* __restrict__ in,
                                 _Float16* __restrict__ out,
                                 int rows, int cols, float scale) {
    __shared__ float tile[32][33];
    int tx = threadIdx.x & 31, ty = threadIdx.x >> 5;   // 32x8 threads
    int r0 = blockIdx.y * 32, c0 = blockIdx.x * 32;
#pragma unroll
    for (int i = 0; i < 32; i += 8)
        tile[ty + i][tx] = in[(size_t)(r0 + ty + i) * cols + c0 + tx];
    __syncthreads();
#pragma unroll
    for (int i = 0; i < 32; i += 8)
        out[(size_t)(c0 + ty + i) * rows + r0 + tx] = (_Float16)(tile[tx][ty + i] * scale);
}

__global__ void init_ctrs(unsigned int* ctr) {
    ctr[threadIdx.x + blockIdx.x * blockDim.x] = 0u;
}

// ---------------- phase 1: x_proj = inputs @ W_xh + b_h ----------------
// R12: m97-structure GEMM (guide §5 ladder step 3): 128x128 tile, BK=32,
// global_load_lds width-16 staging (linear LDS dest = wave-uniform base +
// lane*16), 2-barrier K-loop, 4x4 acc/wave. Replaces the m33-class direct
// global fragment loads (~300 TF -> ~900 TF class on this MFMA).
#define GBK 32
__device__ __forceinline__ void gload_lds16(const _Float16* g, _Float16* l) {
    __builtin_amdgcn_global_load_lds((const __attribute__((address_space(1))) void*)g,
                                     (__attribute__((address_space(3))) void*)l, 16, 0, 0);
}

__global__ __launch_bounds__(256) void gemm_xproj(
    const _Float16* __restrict__ A,      // [M,K] fp16
    const _Float16* __restrict__ BT,     // [N,K] fp16 (W^T, x256)
    const float* __restrict__ bias,
    float* __restrict__ C,               // [M,N] fp32
    int M, int N, int K)
{
    __shared__ _Float16 As[128 * GBK];   // 8 KB, row-major [128][32]
    __shared__ _Float16 Bs[128 * GBK];   // 8 KB

    int tid  = threadIdx.x;
    int wave = tid >> 6;
    int lane = tid & 63;
    int q = lane >> 4;
    int r = lane & 15;
    int m0 = blockIdx.x * 128;
    int n0 = blockIdx.y * 128;
    int wr = (wave >> 1) * 64;           // wave's 64x64 sub-tile
    int wc = (wave & 1) * 64;

    // staging map: chunk = wave*2+i covers LDS bytes [chunk*1024, +1024) =
    // rows chunk*16 .. chunk*16+15 (64 B/row). lane l -> row chunk*16 + (l>>2),
    // k-offset (l&3)*8 elems; LDS dest byte = chunk*1024 + l*16 (linear, HW rule).
    int srow  = lane >> 2;
    int skoff = (lane & 3) * 8;

    f32x4 acc[4][4] = {};
    for (int k0 = 0; k0 < K; k0 += GBK) {
#pragma unroll
        for (int i = 0; i < 2; i++) {
            int chunk = wave * 2 + i;
            int row = chunk * 16 + srow;
            gload_lds16(A  + (size_t)(m0 + row) * K + k0 + skoff, As + chunk * 512);
            gload_lds16(BT + (size_t)(n0 + row) * K + k0 + skoff, Bs + chunk * 512);
        }
        __asm__ volatile("s_waitcnt vmcnt(0)" ::: "memory");
        __syncthreads();

        f16x8 a[4], b[4];
#pragma unroll
        for (int i = 0; i < 4; i++)
            a[i] = *(const f16x8*)(As + (wr + i * 16 + r) * GBK + q * 8);
#pragma unroll
        for (int j = 0; j < 4; j++)
            b[j] = *(const f16x8*)(Bs + (wc + j * 16 + r) * GBK + q * 8);
#pragma unroll
        for (int i = 0; i < 4; i++)
#pragma unroll
            for (int j = 0; j < 4; j++)
                acc[i][j] = __builtin_amdgcn_mfma_f32_16x16x32_f16(a[i], b[j], acc[i][j], 0, 0, 0);
        __syncthreads();
    }
#pragma unroll
    for (int i = 0; i < 4; i++)
#pragma unroll
        for (int j = 0; j < 4; j++)
#pragma unroll
            for (int reg = 0; reg < 4; reg++) {
                int row = m0 + wr + i * 16 + q * 4 + reg;   // C/D: col=lane&15, row=(lane>>4)*4+reg
                int col = n0 + wc + j * 16 + r;
                C[(size_t)row * N + col] = acc[i][j][reg] * W_INV_SCALE + bias[col];
            }
}

// ---------------- phase 2: persistent recurrence ----------------
// R10 structure UNCHANGED (proven 1351 us / 5.27 us/step). R11's in-kernel
// x_proj producer wave REVERTED: its ~100 outstanding per-step L2/LLC loads
// shared the CU vmem queue with the critical-path h-loads and inflated the
// step latency chain 5.27 -> 8.75 us (counter evidence: FETCH only -23MB,
// VGPR 88->128, step +66%). Lesson: don't co-schedule throughput GEMM waves
// with a latency-critical chain on the same CUs.
// Structure: K split across 4 compute waves (512 each) -> 16 loads all in
// flight = ONE latency window; LDS partial reduce by waves 0/1; flat barrier
// (every block's wave0 adds to its group parity line and polls both lines);
// reducer waves own tanh/out/h-store for their column half. Block group g
// (16 rows) has its own 64-block barrier on its own 2 lines. h coherence:
// sc1 write-through stores + fresh chain addresses (plain cached reads).
// Burn wave = wave 4.
template<bool CHAIN>
__global__ __launch_bounds__(TPB, 1) void rnn_persist(
    _Float16* __restrict__ hbase,          // CHAIN: h_0 of chain; else ping buf
    _Float16* __restrict__ hb1,            // pong buf (fallback only)
    const _Float16* __restrict__ WT,       // [H,H] fp16 = W_hh^T x256
    float* __restrict__ out,               // [T,B,H] fp32: x_proj in, h out (in place)
    float* __restrict__ final_out,         // [B,H] fp32
    unsigned int* __restrict__ ctr)        // barrier region (pre-zeroed)
{
    __shared__ f16x8 wfrag[8192];                   // [kb][half][lane] = 128 KB
    __shared__ float part[4][2][256];               // [w][half][lane*4+reg] = 8 KB
    __shared__ __align__(16) _Float16 hsl[16 * 32]; // 1 KB block h tile
    __shared__ int pdone[4];                        // per-wave partial flags
    __shared__ int hdone1, go;                      // monotonic flags

    int tid = threadIdx.x;
    int bid = blockIdx.x;
    int g   = (bid >> 1) & 3;                    // row group (XCD-pair under round-robin)
    int c   = ((bid >> 3) << 1) | (bid & 1);     // col range 0..63
    int n0  = c * 32;
    int row0 = g * 16;                           // block's 16 batch rows

    if (tid == 0) {
        pdone[0] = pdone[1] = pdone[2] = pdone[3] = 0;
        hdone1 = 0; go = 0;
    }

    // one-time W staging into fragment order: idx = (kb*2+half)*64 + l
    for (int idx = tid; idx < 8192; idx += TPB) {
        int kb = idx >> 7, j = (idx >> 6) & 1, l = idx & 63;
        wfrag[idx] = *(const f16x8*)(WT + (size_t)(n0 + j * 16 + (l & 15)) * H_SZ
                                        + kb * 32 + (l >> 4) * 8);
    }
    __syncthreads();   // the ONLY block-wide barrier (covers flag init)

    int wave = tid >> 6, lane = tid & 63;

    if (wave == 4) {
        // dedicated clock keep-alive: 4 independent FMA chains, poll LDS exit flag
        float c0 = 1.0f + lane, c1 = 2.0f, c2 = 3.0f, c3 = 4.0f;
        const float k1 = 1.0000001f, k2 = 1.0e-30f;
        while (__hip_atomic_load(&go, __ATOMIC_RELAXED, __HIP_MEMORY_SCOPE_WORKGROUP) < T_STEPS) {
#pragma unroll
            for (int z = 0; z < 64; z++) {
                c0 = __builtin_fmaf(c0, k1, k2);
                c1 = __builtin_fmaf(c1, k1, k2);
                c2 = __builtin_fmaf(c2, k1, k2);
                c3 = __builtin_fmaf(c3, k1, k2);
            }
        }
        __asm__ volatile("" :: "v"(c0), "v"(c1), "v"(c2), "v"(c3));
        return;
    }

    int q = lane >> 4, r = lane & 15;
    unsigned int* aline = ctr + (g * 2 + (bid & 1)) * 32;   // group parity arrival line

    // reducer-layout x_proj prefetch for t=0 (waves 0,1 only):
    // elem s -> row = (lane>>4)+4s, col = lane&15, column half = wave
    float xp[4];
    if (wave < 2) {
#pragma unroll
        for (int s = 0; s < 4; s++)
            xp[s] = out[(size_t)(row0 + q + 4 * s) * H_SZ + n0 + wave * 16 + r];
    }

    for (int t = 0; t < T_STEPS; t++) {
        const _Float16* hp;
        _Float16*       hn;
        if constexpr (CHAIN) {
            hp = hbase + (size_t)t * HBUF;
            hn = hbase + (size_t)(t + 1) * HBUF;
        } else {
            hp = (t & 1) ? hb1 : hbase;
            hn = (t & 1) ? hbase : hb1;
        }
        float* out_t = out + (size_t)t * B_SZ * H_SZ;
        int tg = t + 1;

        // ---- A stream: this wave's K-slice, all 16 loads in flight ----
        const _Float16* arow = hp + (size_t)(row0 + r) * H_SZ + q * 8;
        f16x8 abuf[16];
#pragma unroll
        for (int p = 0; p < 16; p++) {
            if constexpr (CHAIN) {
                abuf[p] = *(const f16x8*)(arow + (wave * 16 + p) * 32);
            } else {
                union { unsigned long long u[2]; f16x8 v; } au;
                au.u[0] = __hip_atomic_load((unsigned long long*)(arow + (wave * 16 + p) * 32),
                                            __ATOMIC_RELAXED, __HIP_MEMORY_SCOPE_AGENT);
                au.u[1] = __hip_atomic_load((unsigned long long*)(arow + (wave * 16 + p) * 32) + 1,
                                            __ATOMIC_RELAXED, __HIP_MEMORY_SCOPE_AGENT);
                abuf[p] = au.v;
            }
        }
        f32x4 acc[2] = {};
#pragma unroll
        for (int p = 0; p < 16; p++) {
            int kb = wave * 16 + p;
            acc[0] = __builtin_amdgcn_mfma_f32_16x16x32_f16(abuf[p], wfrag[kb * 128 + lane],      acc[0], 0, 0, 0);
            acc[1] = __builtin_amdgcn_mfma_f32_16x16x32_f16(abuf[p], wfrag[kb * 128 + 64 + lane], acc[1], 0, 0, 0);
        }

        // partials to LDS (b128, conflict-free), then flag
#pragma unroll
        for (int h = 0; h < 2; h++)
            *(f32x4*)&part[wave][h][lane * 4] = acc[h];
        __asm__ volatile("s_waitcnt lgkmcnt(0)" ::: "memory");
        if (lane == 0)
            __hip_atomic_store(&pdone[wave], tg, __ATOMIC_RELAXED, __HIP_MEMORY_SCOPE_WORKGROUP);

        if (wave >= 2) {
            if (t == T_STEPS - 1) break;
            while (__hip_atomic_load(&go, __ATOMIC_RELAXED, __HIP_MEMORY_SCOPE_WORKGROUP) < tg) { }
            continue;
        }

        // ---- reducer path (wave 0 = col half 0, wave 1 = col half 1) ----
        for (int w = 0; w < 4; w++)
            if (w != wave)
                while (__hip_atomic_load(&pdone[w], __ATOMIC_RELAXED, __HIP_MEMORY_SCOPE_WORKGROUP) < tg) { }
        __asm__ volatile("" ::: "memory");

        bool last = (t == T_STEPS - 1);
#pragma unroll
        for (int s = 0; s < 4; s++) {
            int row = q + 4 * s;                  // local row 0..15
            int idx = (s * 16 + r) * 4 + q;       // producer layout: ((row>>2)*16+col)*4+(row&3)
            float sum = part[0][wave][idx] + part[1][wave][idx]
                      + part[2][wave][idx] + part[3][wave][idx];
            float v = tanhf(sum * W_INV_SCALE + xp[s]);
            size_t o = (size_t)(row0 + row) * H_SZ + n0 + wave * 16 + r;
            out_t[o] = v;
            if (last) final_out[o] = v;
            hsl[row * 32 + wave * 16 + r] = (_Float16)v;
        }
        if (last) {
            if (wave == 0 && lane == 0)
                __hip_atomic_store(&go, T_STEPS, __ATOMIC_RELAXED, __HIP_MEMORY_SCOPE_WORKGROUP);
            break;
        }

        // prefetch next step's x_proj (h-independent; overlaps h store)
        const float* out_t1 = out_t + B_SZ * H_SZ;
#pragma unroll
        for (int s = 0; s < 4; s++)
            xp[s] = out_t1[(size_t)(row0 + q + 4 * s) * H_SZ + n0 + wave * 16 + r];

        // h store: this wave's column half, 16 rows x 4 ull = 64 ull, 1/lane
        __asm__ volatile("s_waitcnt lgkmcnt(0)" ::: "memory");
        {
            int rl = lane >> 2, pi = wave * 4 + (lane & 3);
            unsigned long long vv = ((const unsigned long long*)hsl)[rl * 8 + pi];
            __hip_atomic_store((unsigned long long*)(hn + (size_t)(row0 + rl) * H_SZ + n0) + pi,
                               vv, __ATOMIC_RELAXED, __HIP_MEMORY_SCOPE_AGENT);
        }
        __builtin_amdgcn_s_waitcnt(0);   // h stores acked at coherence point

        if (wave == 1) {
            if (lane == 0)
                __hip_atomic_store(&hdone1, tg, __ATOMIC_RELAXED, __HIP_MEMORY_SCOPE_WORKGROUP);
            while (__hip_atomic_load(&go, __ATOMIC_RELAXED, __HIP_MEMORY_SCOPE_WORKGROUP) < tg) { }
            continue;
        }
        // wave 0: group barrier (flat: add + poll both parity lines)
        while (__hip_atomic_load(&hdone1, __ATOMIC_RELAXED, __HIP_MEMORY_SCOPE_WORKGROUP) < tg) { }
        if (lane == 0)
            __hip_atomic_fetch_add(aline, 1u, __ATOMIC_RELAXED, __HIP_MEMORY_SCOPE_AGENT);
        unsigned int line_tgt = (unsigned int)tg * 32u;
        for (;;) {
            unsigned int v = __hip_atomic_load(ctr + (g * 2 + (lane & 1)) * 32,
                                               __ATOMIC_RELAXED, __HIP_MEMORY_SCOPE_AGENT);
            if (__ballot(v < line_tgt) == 0ull) break;
        }
        if (lane == 0)
            __hip_atomic_store(&go, tg, __ATOMIC_RELAXED, __HIP_MEMORY_SCOPE_WORKGROUP);
    }
}

// ---------------- launcher ----------------

extern "C" void kernel_launch(void* const* d_in, const int* in_sizes, int n_in,
                              void* d_out, int out_size, void* d_ws, size_t ws_size,
                              hipStream_t stream) {
    const float* inputs = (const float*)d_in[0];   // [T,B,D]
    const float* state  = (const float*)d_in[1];   // [B,H]
    const float* W_xh   = (const float*)d_in[2];   // [D,H]
    const float* W_hh   = (const float*)d_in[3];   // [H,H]
    const float* b_h    = (const float*)d_in[4];   // [H]
    float* out = (float*)d_out;
    char* ws = (char*)d_ws;

    const size_t MB = 1ull << 20;
    // chain layout: [WxT 4MB][WhT 8MB][ctr 8KB][h chain: 257 x 256KB]
    // inputs_f16 (32 MB, dead after gemm) aliases chain slots h_1..h_128.
    const size_t OFF_WXT   = 0;
    const size_t OFF_WHT   = 4 * MB;
    const size_t OFF_CTR   = 12 * MB;
    const size_t OFF_CHAIN = 12 * MB + 8192;
    const size_t NEED_CHAIN = OFF_CHAIN + (size_t)(T_STEPS + 1) * HBUF * 2;

    // fallback (ping-pong) layout
    const size_t F_IN  = 0;
    const size_t F_WXT = F_IN  + (size_t)T_STEPS * B_SZ * D_SZ * 2;
    const size_t F_WHT = F_WXT + (size_t)H_SZ * D_SZ * 2;
    const size_t F_H0  = F_WHT + (size_t)H_SZ * H_SZ * 2;
    const size_t F_H1  = F_H0  + (size_t)HBUF * 2;
    const size_t F_CTR = F_H1  + (size_t)HBUF * 2;
    const size_t NEED_PP = F_CTR + 4096;

    const int n_in_el = T_STEPS * B_SZ * D_SZ;   // 16,777,216 (div by 4)
    dim3 g1((T_STEPS * B_SZ) / 128, H_SZ / 128);
    float* final_out = out + (size_t)T_STEPS * B_SZ * H_SZ;

    if (ws_size >= NEED_CHAIN) {
        _Float16* WxT    = (_Float16*)(ws + OFF_WXT);
        _Float16* WhT    = (_Float16*)(ws + OFF_WHT);
        unsigned int* ctr = (unsigned int*)(ws + OFF_CTR);
        _Float16* hchain = (_Float16*)(ws + OFF_CHAIN);          // h_0
        _Float16* inputs_f16 = hchain + HBUF;                    // alias h_1..h_128
        _Float16* hb1 = nullptr;

        cvt_f32_f16<<<(n_in_el / 4 + 255) / 256, 256, 0, stream>>>(inputs, inputs_f16, n_in_el / 4, 1.0f);
        transpose_to_f16<<<dim3(H_SZ / 32, D_SZ / 32), 256, 0, stream>>>(W_xh, WxT, D_SZ, H_SZ, W_SCALE);
        transpose_to_f16<<<dim3(H_SZ / 32, H_SZ / 32), 256, 0, stream>>>(W_hh, WhT, H_SZ, H_SZ, W_SCALE);
        cvt_f32_f16<<<(B_SZ * H_SZ / 4 + 255) / 256, 256, 0, stream>>>(state, hchain, B_SZ * H_SZ / 4, 1.0f);
        init_ctrs<<<4, 256, 0, stream>>>(ctr);

        gemm_xproj<<<g1, 256, 0, stream>>>(inputs_f16, WxT, b_h, out,
                                           T_STEPS * B_SZ, H_SZ, D_SZ);

        void* args[] = { (void*)&hchain, (void*)&hb1, (void*)&WhT,
                         (void*)&out, (void*)&final_out, (void*)&ctr };
        hipLaunchCooperativeKernel((void*)rnn_persist<true>, dim3(NBLK), dim3(TPB),
                                   args, 0, stream);
    } else {
        if (ws_size < NEED_PP) return;
        _Float16* inputs_f16 = (_Float16*)(ws + F_IN);
        _Float16* WxT    = (_Float16*)(ws + F_WXT);
        _Float16* WhT    = (_Float16*)(ws + F_WHT);
        _Float16* hbuf0  = (_Float16*)(ws + F_H0);
        _Float16* hbuf1  = (_Float16*)(ws + F_H1);
        unsigned int* ctr = (unsigned int*)(ws + F_CTR);

        cvt_f32_f16<<<(n_in_el / 4 + 255) / 256, 256, 0, stream>>>(inputs, inputs_f16, n_in_el / 4, 1.0f);
        transpose_to_f16<<<dim3(H_SZ / 32, D_SZ / 32), 256, 0, stream>>>(W_xh, WxT, D_SZ, H_SZ, W_SCALE);
        transpose_to_f16<<<dim3(H_SZ / 32, H_SZ / 32), 256, 0, stream>>>(W_hh, WhT, H_SZ, H_SZ, W_SCALE);
        cvt_f32_f16<<<(B_SZ * H_SZ / 4 + 255) / 256, 256, 0, stream>>>(state, hbuf0, B_SZ * H_SZ / 4, 1.0f);
        init_ctrs<<<4, 256, 0, stream>>>(ctr);

        gemm_xproj<<<g1, 256, 0, stream>>>(inputs_f16, WxT, b_h, out,
                                           T_STEPS * B_SZ, H_SZ, D_SZ);

        void* args[] = { (void*)&hbuf0, (void*)&hbuf1, (void*)&WhT,
                         (void*)&out, (void*)&final_out, (void*)&ctr };
        hipLaunchCooperativeKernel((void*)rnn_persist<false>, dim3(NBLK), dim3(TPB),
                                   args, 0, stream);
    }
}